// Round 1
// baseline (297.358 us; speedup 1.0000x reference)
//
#include <hip/hip_runtime.h>
#include <cstdint>

// GF(2) encoder: out[b][n] = popcount-parity( xbits[b] & gbits[n] )
// B=131072, K=512 (=16 u32 words), N=1024.

// ---------------------------------------------------------------------------
// Kernel 1/2: pack 0.0/1.0 floats into bitmasks via wave ballot.
// Wave's 64 lanes read 64 consecutive floats -> one u64 mask, lane 0 stores.
// Requires n % 64 == 0 and grid*block stride a multiple of 64 (both hold).
__global__ void pack_bits_kernel(const float* __restrict__ in,
                                 unsigned long long* __restrict__ out,
                                 long long n) {
    const long long stride = (long long)gridDim.x * blockDim.x;
    for (long long i = (long long)blockIdx.x * blockDim.x + threadIdx.x;
         i < n; i += stride) {
        unsigned long long m = __ballot(in[i] != 0.0f);
        if ((threadIdx.x & 63) == 0) out[i >> 6] = m;
    }
}

// ---------------------------------------------------------------------------
// Kernel 3: main GF(2) matmul-parity.
// Block = 256 threads, each thread owns 4 consecutive columns (covers N=1024).
// Each block processes 64 consecutive rows; G fragments live in registers,
// the packed x row is loaded with a wave-uniform address (scalar loads).
__global__ __launch_bounds__(256) void gf2_encode_kernel(
    const uint32_t* __restrict__ xp,   // [B][16] packed rows of x
    const uint32_t* __restrict__ gp,   // [N][16] packed rows of G
    float* __restrict__ out) {         // [B][N]
    const int n0 = threadIdx.x << 2;   // first of this thread's 4 columns

    // Load this thread's 4 G rows (4 x 16 u32 = 64 VGPRs), once.
    uint32_t g[4][16];
#pragma unroll
    for (int j = 0; j < 4; ++j) {
        const uint4* gr = reinterpret_cast<const uint4*>(gp + (size_t)(n0 + j) * 16);
        uint4 a = gr[0], b = gr[1], c = gr[2], d = gr[3];
        g[j][0] = a.x;  g[j][1] = a.y;  g[j][2] = a.z;  g[j][3] = a.w;
        g[j][4] = b.x;  g[j][5] = b.y;  g[j][6] = b.z;  g[j][7] = b.w;
        g[j][8] = c.x;  g[j][9] = c.y;  g[j][10] = c.z; g[j][11] = c.w;
        g[j][12] = d.x; g[j][13] = d.y; g[j][14] = d.z; g[j][15] = d.w;
    }

    const long long b0 = (long long)blockIdx.x * 64;
    for (int r = 0; r < 64; ++r) {
        const long long b = b0 + r;
        // Wave-uniform address -> scalar loads (s_load_dwordx4), K$-served.
        const uint4* xr = reinterpret_cast<const uint4*>(xp + (size_t)b * 16);
        uint4 xa = xr[0], xb = xr[1], xc = xr[2], xd = xr[3];
        uint32_t x[16] = {xa.x, xa.y, xa.z, xa.w,
                          xb.x, xb.y, xb.z, xb.w,
                          xc.x, xc.y, xc.z, xc.w,
                          xd.x, xd.y, xd.z, xd.w};

        uint32_t acc0 = 0, acc1 = 0, acc2 = 0, acc3 = 0;
#pragma unroll
        for (int w = 0; w < 16; ++w) {
            acc0 ^= x[w] & g[0][w];
            acc1 ^= x[w] & g[1][w];
            acc2 ^= x[w] & g[2][w];
            acc3 ^= x[w] & g[3][w];
        }
        float4 o;
        o.x = (float)(__popc(acc0) & 1);
        o.y = (float)(__popc(acc1) & 1);
        o.z = (float)(__popc(acc2) & 1);
        o.w = (float)(__popc(acc3) & 1);
        reinterpret_cast<float4*>(out + (size_t)b * 1024)[threadIdx.x] = o;
    }
}

// ---------------------------------------------------------------------------
extern "C" void kernel_launch(void* const* d_in, const int* in_sizes, int n_in,
                              void* d_out, int out_size, void* d_ws, size_t ws_size,
                              hipStream_t stream) {
    const float* x = (const float*)d_in[0];   // [B][K] 0/1 floats
    const float* G = (const float*)d_in[1];   // [N][K] 0/1 floats
    float* out = (float*)d_out;               // [B][N]

    const long long B = 131072, K = 512, N = 1024;

    // Workspace layout: gp (N*K/8 = 64 KiB) | xp (B*K/8 = 8 MiB)
    unsigned long long* gp64 = (unsigned long long*)d_ws;
    unsigned long long* xp64 = (unsigned long long*)((char*)d_ws + 65536);

    // Pack G: 524288 elems, 2048 blocks x 256 threads = exactly one elem each.
    pack_bits_kernel<<<2048, 256, 0, stream>>>(G, gp64, N * K);
    // Pack x: 67.1M elems, grid-stride (128 iters/thread).
    pack_bits_kernel<<<2048, 256, 0, stream>>>(x, xp64, B * K);
    // Main: one block per 64 rows.
    gf2_encode_kernel<<<B / 64, 256, 0, stream>>>(
        (const uint32_t*)xp64, (const uint32_t*)gp64, out);
}